// Round 14
// baseline (43.645 us; speedup 1.0000x reference)
//
#include <hip/hip_runtime.h>
#include <stdint.h>

// Problem: x (4096,2048) int32 {0,1}; references (1024,2048) f32 {0,1};
// out (4096,1024) f32 = (hamming - 1024) / (0.5*sqrt(2048)).
// Identity: s=1-2x, t=1-2r in {+-1}: hamming = (2048 - s.t)/2 ->
//   out[b,d] = -(inv_std/2) * dot_pm1(b,d)     (exact integer dot)
// fp4 E2M1: +1=0x2, -1=0xA; MX scales all 1.0 (E8M0 0x7F) -> exact f32 dot.
//
// DIAGNOSTIC ROUND: gemm runs its K-loop REPS=4 times inside one dispatch
// (acc accumulates 4*dot, epilogue scales by scale/4 -- bit-exact), pushing
// its dur above the harness's ~40us fill dispatches so rocprof top-5 shows
// its true MfmaUtil / VALUBusy / Occupancy / LDS-conflict / FETCH counters.
// True per-pass GEMM time = row_dur / 4.
constexpr int B_ROWS = 4096;
constexpr int D_ROWS = 1024;
constexpr int L_LEN  = 2048;
constexpr int LB     = L_LEN / 2;        // 1024 B per row at fp4

using int32x4 = __attribute__((ext_vector_type(4))) int;
using int32x8 = __attribute__((ext_vector_type(8))) int;
using f32x16  = __attribute__((ext_vector_type(16))) float;

// ---------------------------------------------------------------------------
// Kernel 1 (UNCHANGED R11/R12 — control): convert both inputs to +-1 fp4.
// ---------------------------------------------------------------------------
__global__ __launch_bounds__(256) void convert_fp4_kernel(
    const int* __restrict__ x, const float* __restrict__ r,
    uint32_t* __restrict__ xq, uint32_t* __restrict__ rq,
    int groups_x, int groups_total)
{
  const int tid = blockIdx.x * blockDim.x + threadIdx.x;
  const int nth = gridDim.x * blockDim.x;
  for (int g = tid; g < groups_total; g += nth) {
    uint32_t wo;
    if (g < groups_x) {
      const int4 v0 = *reinterpret_cast<const int4*>(x + (size_t)g * 8);
      const int4 v1 = *reinterpret_cast<const int4*>(x + (size_t)g * 8 + 4);
      wo  = (v0.x ? 0xAu : 0x2u);
      wo |= (v0.y ? 0xAu : 0x2u) << 4;
      wo |= (v0.z ? 0xAu : 0x2u) << 8;
      wo |= (v0.w ? 0xAu : 0x2u) << 12;
      wo |= (v1.x ? 0xAu : 0x2u) << 16;
      wo |= (v1.y ? 0xAu : 0x2u) << 20;
      wo |= (v1.z ? 0xAu : 0x2u) << 24;
      wo |= (v1.w ? 0xAu : 0x2u) << 28;
      xq[g] = wo;
    } else {
      const int gr = g - groups_x;
      const float4 v0 = *reinterpret_cast<const float4*>(r + (size_t)gr * 8);
      const float4 v1 = *reinterpret_cast<const float4*>(r + (size_t)gr * 8 + 4);
      wo  = (v0.x != 0.0f ? 0xAu : 0x2u);
      wo |= (v0.y != 0.0f ? 0xAu : 0x2u) << 4;
      wo |= (v0.z != 0.0f ? 0xAu : 0x2u) << 8;
      wo |= (v0.w != 0.0f ? 0xAu : 0x2u) << 12;
      wo |= (v1.x != 0.0f ? 0xAu : 0x2u) << 16;
      wo |= (v1.y != 0.0f ? 0xAu : 0x2u) << 20;
      wo |= (v1.z != 0.0f ? 0xAu : 0x2u) << 24;
      wo |= (v1.w != 0.0f ? 0xAu : 0x2u) << 28;
      rq[gr] = wo;
    }
  }
}

// ---------------------------------------------------------------------------
// Kernel 2: R12's MX-fp4 GEMM (3-buffer counted-vmcnt pipeline), K-loop
// executed REPS=4x as one flat 64-step loop. The 3-buffer rotation and the
// "stage tile s+2" schedule wrap modulo KSTEPS, so the pipeline stays full
// across reps; acc is never reset -> no DCE; out = acc * (scale/4).
// ---------------------------------------------------------------------------
constexpr int BM = 128;
constexpr int BN = 64;
constexpr int BKB = 64;                  // K-step bytes per row (128 elems)
constexpr int KSTEPS = LB / BKB;         // 16
constexpr int REPS = 4;
constexpr int TOT = REPS * KSTEPS;       // 64 steps
constexpr int GRID_D = D_ROWS / BN;      // 16
constexpr int NWG = (B_ROWS / BM) * GRID_D;   // 512

typedef __attribute__((address_space(3))) void       as3_void;
typedef const __attribute__((address_space(1))) void as1_cvoid;

__device__ __forceinline__ void gload_lds16(const void* g, void* l) {
  __builtin_amdgcn_global_load_lds((as1_cvoid*)g, (as3_void*)l, 16, 0, 0);
}

__global__ __launch_bounds__(256) void gemm_fp4_kernel(
    const uint8_t* __restrict__ Aq, const uint8_t* __restrict__ Bq,
    float* __restrict__ out)
{
  __shared__ __align__(16) uint8_t A_lds[3][BM * BKB];   // 3 x 8 KB
  __shared__ __align__(16) uint8_t B_lds[3][BN * BKB];   // 3 x 4 KB

  const int lin = blockIdx.x;
  const int swz = (lin & 7) * (NWG / 8) + (lin >> 3);   // bijective, 512%8==0
  const int bm  = (swz / GRID_D) * BM;
  const int bn  = (swz % GRID_D) * BN;

  const int t    = threadIdx.x;
  const int lane = t & 63;
  const int w    = t >> 6;          // wave 0..3
  const int wr   = w >> 1;          // wave row (m): tile rows wr*64..+64
  const int wc   = w & 1;           // wave col (n): tile cols wc*32..+32

  const uint8_t* gA[2];
#pragma unroll
  for (int c = 0; c < 2; ++c) {
    const int r = w * 32 + c * 16 + (lane >> 2);
    gA[c] = Aq + (size_t)(bm + r) * LB + (((lane & 3) ^ ((r >> 1) & 3)) * 16);
  }
  const int rB = w * 16 + (lane >> 2);
  const uint8_t* gB0 =
      Bq + (size_t)(bn + rB) * LB + (((lane & 3) ^ ((rB >> 1) & 3)) * 16);

#define STAGE(buf, k0b) do {                                                  \
    _Pragma("unroll") for (int _c = 0; _c < 2; ++_c)                          \
      gload_lds16(gA[_c] + (k0b), A_lds[buf] + (w * 32 + _c * 16) * BKB);     \
    gload_lds16(gB0 + (k0b), B_lds[buf] + (w * 16) * BKB);                    \
  } while (0)

#define COMPUTE(cur) do {                                                     \
    _Pragma("unroll") for (int kc = 0; kc < 2; ++kc) {                        \
      const int rowB = wc * 32 + (lane & 31);                                 \
      const int qB   = 2 * kc + (lane >> 5);                                  \
      const int32x4 b4 = *reinterpret_cast<const int32x4*>(                   \
          B_lds[cur] + rowB * BKB + ((qB ^ ((rowB >> 1) & 3)) * 16));         \
      const int32x8 b8 = {b4[0], b4[1], b4[2], b4[3], 0, 0, 0, 0};            \
      _Pragma("unroll") for (int f = 0; f < 2; ++f) {                         \
        const int rowA = wr * 64 + f * 32 + (lane & 31);                      \
        const int qA   = 2 * kc + (lane >> 5);                                \
        const int32x4 a4 = *reinterpret_cast<const int32x4*>(                 \
            A_lds[cur] + rowA * BKB + ((qA ^ ((rowA >> 1) & 3)) * 16));       \
        const int32x8 a8 = {a4[0], a4[1], a4[2], a4[3], 0, 0, 0, 0};          \
        acc[f] = __builtin_amdgcn_mfma_scale_f32_32x32x64_f8f6f4(             \
            a8, b8, acc[f], 4, 4, 0, 0x7F7F7F7F, 0, 0x7F7F7F7F);              \
      }                                                                       \
    } } while (0)

  f32x16 acc[2] = {};

  STAGE(0, 0);
  STAGE(1, BKB);                    // 6 loads in flight

#pragma unroll 3
  for (int s = 0; s < TOT - 1; ++s) {         // 63 iters; s%3 static
    const int cur = s % 3;
    asm volatile("s_waitcnt vmcnt(3)" ::: "memory");  // own tile-s landed
    __builtin_amdgcn_sched_barrier(0);                // rule #18
    __builtin_amdgcn_s_barrier();                     // raw: no full drain
    STAGE((s + 2) % 3, ((s + 2) & (KSTEPS - 1)) * BKB);  // wraps across reps
    COMPUTE(cur);
  }
  // Peeled final step (s = 63, buf 63 % 3 = 0).
  asm volatile("s_waitcnt vmcnt(0)" ::: "memory");
  __builtin_amdgcn_sched_barrier(0);
  __builtin_amdgcn_s_barrier();
  COMPUTE(0);

#undef STAGE
#undef COMPUTE

  // Epilogue: verified 32x32 C/D layout: col = lane&31,
  // row = (reg&3) + 8*(reg>>2) + 4*(lane>>5). acc holds REPS*dot; the
  // (scale/REPS) compile-time constant makes the product bit-identical to
  // dot*scale (4*dot is an exact f32 integer; /4 is a power of two).
  const float scale = -0.5f * 0.04419417382415922f / (float)REPS;
  const int col = bn + wc * 32 + (lane & 31);
#pragma unroll
  for (int f = 0; f < 2; ++f) {
#pragma unroll
    for (int reg = 0; reg < 16; ++reg) {
      const int row = bm + wr * 64 + f * 32 + (reg & 3) + 8 * (reg >> 2)
                    + 4 * (lane >> 5);
      out[(size_t)row * D_ROWS + col] = acc[f][reg] * scale;
    }
  }
}

extern "C" void kernel_launch(void* const* d_in, const int* in_sizes, int n_in,
                              void* d_out, int out_size, void* d_ws, size_t ws_size,
                              hipStream_t stream) {
  const int*   x = (const int*)d_in[0];     // (4096, 2048) int32
  const float* r = (const float*)d_in[1];   // (1024, 2048) float32
  float*     out = (float*)d_out;           // (4096, 1024) float32

  uint8_t* Aq = (uint8_t*)d_ws;                         // 4 MiB (4096x1024 B)
  uint8_t* Bq = Aq + (size_t)B_ROWS * LB;               // 1 MiB (1024x1024 B)

  const int groups_x = B_ROWS * L_LEN / 8;              // 1048576
  const int groups_r = D_ROWS * L_LEN / 8;              // 262144
  const int groups_total = groups_x + groups_r;

  convert_fp4_kernel<<<2048, 256, 0, stream>>>(
      x, r, (uint32_t*)Aq, (uint32_t*)Bq, groups_x, groups_total);

  gemm_fp4_kernel<<<NWG, 256, 0, stream>>>(Aq, Bq, out);  // 512 blocks
}

// Round 15
// 25.004 us; speedup vs baseline: 1.7455x; 1.7455x over previous
//
#include <hip/hip_runtime.h>
#include <stdint.h>

// Problem: x (4096,2048) int32 {0,1}; references (1024,2048) f32 {0,1};
// out (4096,1024) f32 = (hamming - 1024) / (0.5*sqrt(2048)).
// Identity: s=1-2x, t=1-2r in {+-1}: hamming = (2048 - s.t)/2 ->
//   out[b,d] = -(inv_std/2) * dot_pm1(b,d)     (exact integer dot)
// fp4 E2M1: +1=0x2, -1=0xA; MX scales all 1.0 (E8M0 0x7F) -> exact f32 dot.
constexpr int B_ROWS = 4096;
constexpr int D_ROWS = 1024;
constexpr int L_LEN  = 2048;
constexpr int LB     = L_LEN / 2;        // 1024 B per row at fp4

using int32x4 = __attribute__((ext_vector_type(4))) int;
using int32x8 = __attribute__((ext_vector_type(8))) int;
using f32x16  = __attribute__((ext_vector_type(16))) float;

// ---------------------------------------------------------------------------
// Kernel 1 v2: COALESCED convert (the real pig: R14 diagnostic pinned the
// old stride-32 version at ~17 us ~ 2.6 TB/s).
// One wave per 512-elem row-segment: lane reads int4 at base+lane*4 and
// base+256+lane*4 -> two perfectly lane-contiguous 1 KB wave-reads (the
// R2/R7 pattern that measured ~8 us for 40 MB). Write: one dword per lane,
// 256 B contiguous per wave.
// k-permutation induced (dword d of a row holds elems seg*512+4*(d&63)+0..3
// and seg*512+256+4*(d&63)+0..3) is row-uniform and identical for A and B
// -> MFMA dot is exactly preserved (hardware pairs A/B byte positions).
// ---------------------------------------------------------------------------
constexpr int XSEGS = B_ROWS * 4;              // 16384 x-segments (512 elems)
constexpr int RSEGS = D_ROWS * 4;              //  4096 r-segments
constexpr int CVT_BLOCKS = (XSEGS + RSEGS) / 4;  // 5120 blocks of 4 waves

__global__ __launch_bounds__(256) void convert_fp4_kernel(
    const int* __restrict__ x, const float* __restrict__ r,
    uint32_t* __restrict__ xq, uint32_t* __restrict__ rq)
{
  const int wave = (int)((blockIdx.x * blockDim.x + threadIdx.x) >> 6);
  const int lane = threadIdx.x & 63;
  uint32_t wo;
  if (wave < XSEGS) {                        // wave-uniform branch
    const int row = wave >> 2, seg = wave & 3;
    const int* s = x + (size_t)row * L_LEN + seg * 512 + lane * 4;
    const int4 v0 = *reinterpret_cast<const int4*>(s);
    const int4 v1 = *reinterpret_cast<const int4*>(s + 256);
    wo  = (v0.x ? 0xAu : 0x2u);
    wo |= (v0.y ? 0xAu : 0x2u) << 4;
    wo |= (v0.z ? 0xAu : 0x2u) << 8;
    wo |= (v0.w ? 0xAu : 0x2u) << 12;
    wo |= (v1.x ? 0xAu : 0x2u) << 16;
    wo |= (v1.y ? 0xAu : 0x2u) << 20;
    wo |= (v1.z ? 0xAu : 0x2u) << 24;
    wo |= (v1.w ? 0xAu : 0x2u) << 28;
    xq[row * 256 + seg * 64 + lane] = wo;
  } else {
    const int sr  = wave - XSEGS;
    const int row = sr >> 2, seg = sr & 3;
    const float* s = r + (size_t)row * L_LEN + seg * 512 + lane * 4;
    const float4 v0 = *reinterpret_cast<const float4*>(s);
    const float4 v1 = *reinterpret_cast<const float4*>(s + 256);
    wo  = (v0.x != 0.0f ? 0xAu : 0x2u);
    wo |= (v0.y != 0.0f ? 0xAu : 0x2u) << 4;
    wo |= (v0.z != 0.0f ? 0xAu : 0x2u) << 8;
    wo |= (v0.w != 0.0f ? 0xAu : 0x2u) << 12;
    wo |= (v1.x != 0.0f ? 0xAu : 0x2u) << 16;
    wo |= (v1.y != 0.0f ? 0xAu : 0x2u) << 20;
    wo |= (v1.z != 0.0f ? 0xAu : 0x2u) << 24;
    wo |= (v1.w != 0.0f ? 0xAu : 0x2u) << 28;
    rq[row * 256 + seg * 64 + lane] = wo;
  }
}

// ---------------------------------------------------------------------------
// Kernel 2 (R12 VERBATIM — control; REPS diagnostic removed): MX-fp4 GEMM,
// 3-buffer counted-vmcnt pipeline (measured: K-loop 6.2 us, total ~8 us).
// ---------------------------------------------------------------------------
constexpr int BM = 128;
constexpr int BN = 64;
constexpr int BKB = 64;                  // K-step bytes per row (128 elems)
constexpr int KSTEPS = LB / BKB;         // 16
constexpr int GRID_D = D_ROWS / BN;      // 16
constexpr int NWG = (B_ROWS / BM) * GRID_D;   // 512

typedef __attribute__((address_space(3))) void       as3_void;
typedef const __attribute__((address_space(1))) void as1_cvoid;

__device__ __forceinline__ void gload_lds16(const void* g, void* l) {
  __builtin_amdgcn_global_load_lds((as1_cvoid*)g, (as3_void*)l, 16, 0, 0);
}

__global__ __launch_bounds__(256) void gemm_fp4_kernel(
    const uint8_t* __restrict__ Aq, const uint8_t* __restrict__ Bq,
    float* __restrict__ out)
{
  __shared__ __align__(16) uint8_t A_lds[3][BM * BKB];   // 3 x 8 KB
  __shared__ __align__(16) uint8_t B_lds[3][BN * BKB];   // 3 x 4 KB

  const int lin = blockIdx.x;
  const int swz = (lin & 7) * (NWG / 8) + (lin >> 3);   // bijective, 512%8==0
  const int bm  = (swz / GRID_D) * BM;
  const int bn  = (swz % GRID_D) * BN;

  const int t    = threadIdx.x;
  const int lane = t & 63;
  const int w    = t >> 6;          // wave 0..3
  const int wr   = w >> 1;          // wave row (m): tile rows wr*64..+64
  const int wc   = w & 1;           // wave col (n): tile cols wc*32..+32

  const uint8_t* gA[2];
#pragma unroll
  for (int c = 0; c < 2; ++c) {
    const int r = w * 32 + c * 16 + (lane >> 2);
    gA[c] = Aq + (size_t)(bm + r) * LB + (((lane & 3) ^ ((r >> 1) & 3)) * 16);
  }
  const int rB = w * 16 + (lane >> 2);
  const uint8_t* gB0 =
      Bq + (size_t)(bn + rB) * LB + (((lane & 3) ^ ((rB >> 1) & 3)) * 16);

#define STAGE(buf, k0b) do {                                                  \
    _Pragma("unroll") for (int _c = 0; _c < 2; ++_c)                          \
      gload_lds16(gA[_c] + (k0b), A_lds[buf] + (w * 32 + _c * 16) * BKB);     \
    gload_lds16(gB0 + (k0b), B_lds[buf] + (w * 16) * BKB);                    \
  } while (0)

#define COMPUTE(cur) do {                                                     \
    _Pragma("unroll") for (int kc = 0; kc < 2; ++kc) {                        \
      const int rowB = wc * 32 + (lane & 31);                                 \
      const int qB   = 2 * kc + (lane >> 5);                                  \
      const int32x4 b4 = *reinterpret_cast<const int32x4*>(                   \
          B_lds[cur] + rowB * BKB + ((qB ^ ((rowB >> 1) & 3)) * 16));         \
      const int32x8 b8 = {b4[0], b4[1], b4[2], b4[3], 0, 0, 0, 0};            \
      _Pragma("unroll") for (int f = 0; f < 2; ++f) {                         \
        const int rowA = wr * 64 + f * 32 + (lane & 31);                      \
        const int qA   = 2 * kc + (lane >> 5);                                \
        const int32x4 a4 = *reinterpret_cast<const int32x4*>(                 \
            A_lds[cur] + rowA * BKB + ((qA ^ ((rowA >> 1) & 3)) * 16));       \
        const int32x8 a8 = {a4[0], a4[1], a4[2], a4[3], 0, 0, 0, 0};          \
        acc[f] = __builtin_amdgcn_mfma_scale_f32_32x32x64_f8f6f4(             \
            a8, b8, acc[f], 4, 4, 0, 0x7F7F7F7F, 0, 0x7F7F7F7F);              \
      }                                                                       \
    } } while (0)

  f32x16 acc[2] = {};

  STAGE(0, 0);
  STAGE(1, BKB);                    // 6 loads in flight

#pragma unroll 3
  for (int ks = 0; ks < KSTEPS - 1; ++ks) {   // 15 iters, cur/(ks+2)%3 static
    const int cur = ks % 3;
    asm volatile("s_waitcnt vmcnt(3)" ::: "memory");  // tile ks landed
    __builtin_amdgcn_sched_barrier(0);                // rule #18
    __builtin_amdgcn_s_barrier();                     // raw: no vmcnt(0) drain
    if (ks + 2 < KSTEPS) STAGE((ks + 2) % 3, (ks + 2) * BKB);
    COMPUTE(cur);
  }
  asm volatile("s_waitcnt vmcnt(0)" ::: "memory");
  __builtin_amdgcn_sched_barrier(0);
  __builtin_amdgcn_s_barrier();
  COMPUTE(0);

#undef STAGE
#undef COMPUTE

  // Epilogue: verified 32x32 C/D layout: col = lane&31,
  // row = (reg&3) + 8*(reg>>2) + 4*(lane>>5).
  const float scale = -0.5f * 0.04419417382415922f;
  const int col = bn + wc * 32 + (lane & 31);
#pragma unroll
  for (int f = 0; f < 2; ++f) {
#pragma unroll
    for (int reg = 0; reg < 16; ++reg) {
      const int row = bm + wr * 64 + f * 32 + (reg & 3) + 8 * (reg >> 2)
                    + 4 * (lane >> 5);
      out[(size_t)row * D_ROWS + col] = acc[f][reg] * scale;
    }
  }
}

extern "C" void kernel_launch(void* const* d_in, const int* in_sizes, int n_in,
                              void* d_out, int out_size, void* d_ws, size_t ws_size,
                              hipStream_t stream) {
  const int*   x = (const int*)d_in[0];     // (4096, 2048) int32
  const float* r = (const float*)d_in[1];   // (1024, 2048) float32
  float*     out = (float*)d_out;           // (4096, 1024) float32

  uint8_t* Aq = (uint8_t*)d_ws;                         // 4 MiB (4096x1024 B)
  uint8_t* Bq = Aq + (size_t)B_ROWS * LB;               // 1 MiB (1024x1024 B)

  convert_fp4_kernel<<<CVT_BLOCKS, 256, 0, stream>>>(
      x, r, (uint32_t*)Aq, (uint32_t*)Bq);

  gemm_fp4_kernel<<<NWG, 256, 0, stream>>>(Aq, Bq, out);  // 512 blocks
}